// Round 15
// baseline (307.412 us; speedup 1.0000x reference)
//
#include <hip/hip_runtime.h>
#include <hip/hip_bf16.h>

#define SEQ 16384
#define DIM 1280
#define NHEAD 16
#define HD 80
#define NWIN 256   // SEQ / 64
#define QKV_N 3840 // 3 * DIM
#define GK 1280    // K of both GEMMs
#define NT 20      // GK / 64

typedef __attribute__((ext_vector_type(8))) short bf16x8;
typedef __attribute__((ext_vector_type(8))) unsigned short ushort8;
typedef __attribute__((ext_vector_type(4))) float f32x4;

__device__ inline unsigned short f2bf(float x) {
    union { __hip_bfloat16 b; unsigned short u; } cv;
    cv.b = __float2bfloat16(x);
    return cv.u;
}
__device__ inline float bf2f(unsigned short u) {
    union { unsigned int i; float f; } cv;
    cv.i = ((unsigned int)u) << 16;
    return cv.f;
}

// async global->LDS, 16B per lane, wave-uniform LDS base + lane*16
#define GLD16(g, l) __builtin_amdgcn_global_load_lds( \
    (const __attribute__((address_space(1))) void*)(g), \
    (__attribute__((address_space(3))) void*)(l), 16, 0, 0)

#define SBAR() asm volatile("s_barrier" ::: "memory")

// ---------------------------------------------------------------------------
// merged f32 -> bf16 convert for all three buffers (one dispatch, r12-best).
// ---------------------------------------------------------------------------
#define CVT_B0 10240   // SEQ*DIM      / 2048
#define CVT_B1 12640   // + QKV_N*DIM  / 2048
#define CVT_B2 13440   // + DIM*DIM    / 2048
__global__ __launch_bounds__(256) void cvt_all(
    const float* __restrict__ s0, unsigned short* __restrict__ d0,
    const float* __restrict__ s1, unsigned short* __restrict__ d1,
    const float* __restrict__ s2, unsigned short* __restrict__ d2)
{
    const int b = blockIdx.x;
    const float* s; unsigned short* d; long off;
    if (b < CVT_B0)      { s = s0; d = d0; off = (long)b * 2048; }
    else if (b < CVT_B1) { s = s1; d = d1; off = (long)(b - CVT_B0) * 2048; }
    else                 { s = s2; d = d2; off = (long)(b - CVT_B1) * 2048; }
    const long i = off + (long)threadIdx.x * 8;
    const float4 a = *(const float4*)(s + i);
    const float4 c = *(const float4*)(s + i + 4);
    ushort8 o;
    o[0] = f2bf(a.x); o[1] = f2bf(a.y); o[2] = f2bf(a.z); o[3] = f2bf(a.w);
    o[4] = f2bf(c.x); o[5] = f2bf(c.y); o[6] = f2bf(c.z); o[7] = f2bf(c.w);
    *(ushort8*)(d + i) = o;
}

// ---------------------------------------------------------------------------
// [QKV] Ring-buffered phased GEMM: 256x256, BK=64, 512 thr (8 waves 2Mx4N,
// 128x64/wave — sp geometry, proven 0-conflict swizzle on 64-elem rows).
// LDS 160 KiB exactly: A ring 3x32K (issued 2 tiles ahead) + B dbuf 2x32K
// (issued 1 tile ahead). Per tile: top {vmcnt(4); SBAR} — waits only loads
// >= 1 full tile old (issue order ... A(kt), B(kt), A(kt+1) => vmcnt(4)
// leaves exactly A(kt+1) in flight); never 0 except last tile. Then 2
// phases (kk0/kk1), each: {12 ds_reads; stage-issue (B(kt+1) in ph0,
// A(kt+2) in ph1); SBAR; lgkmcnt(0)+sched_barrier(0) [rule 18]; setprio;
// 32 MFMA; setprio(0); SBAR-or-top}. This combines r6's barrier-spread
// LDS reads (no burst queueing) with sp's deep prefetch (no vmcnt stall
// amplified by barriers) — the two halves that each alone plateaued at 43%.
// Race-freedom: stage writes target slot (kt+2)%3 / region (kt+1)&1, whose
// last reads (tile kt-1) retire at each wave's lgkmcnt(0) before it reaches
// the kt-top barrier, which precedes all issue points. W->R via top vmcnt.
// ---------------------------------------------------------------------------
template <int OUT_BF16>
__global__ __launch_bounds__(512, 2) void gemm_nt_bf16_r3(
    const unsigned short* __restrict__ A,   // [M][GK] bf16
    const unsigned short* __restrict__ B,   // [N][GK] bf16
    const float* __restrict__ bias,         // [N]
    void* __restrict__ outp,                // [M][N] f32 or bf16
    int N, int nbx)                         // nbx = N/256
{
    __shared__ unsigned short sh[81920];    // A ring 3*16384 | B dbuf 2*16384

    const int t = threadIdx.x;
    const int w = t >> 6;
    const int lane = t & 63;
    const int l15 = lane & 15;
    const int g = lane >> 4;

    // T1: XCD swizzle (gridDim.x multiple of 8)
    const int cpx = gridDim.x >> 3;
    const int bid = blockIdx.x;
    const int wg = (bid & 7) * cpx + (bid >> 3);
    const int bm = (wg / nbx) * 256;
    const int bn = (wg % nbx) * 256;

    const int wr = (w >> 2) * 128;   // wave rows [wr, wr+128)
    const int wc = (w & 3) * 64;     // wave cols [wc, wc+64)

    // staging map (sp-identical): thread t covers row tr = t>>3 of each
    // 64-row block, slot t&7; pre-swizzled source col = slot*8 ^ ((tr&7)<<3)
    const int tr = t >> 3;
    const int colsw = ((t & 7) * 8) ^ (((t >> 3) & 7) << 3);
    const unsigned short* gA[4];
    const unsigned short* gB[4];
#pragma unroll
    for (int j = 0; j < 4; ++j) {
        gA[j] = A + (size_t)(bm + j * 64 + tr) * GK + colsw;
        gB[j] = B + (size_t)(bn + j * 64 + tr) * GK + colsw;
    }
    const int wub = (t & ~63) * 8;   // wave-uniform LDS elem base

    // frag offsets: LDS[row*64 + e] = global[row][e ^ ((row&7)<<3)]
    const int sw = (l15 & 7) << 3;
    const int fk0 = (g * 8) ^ sw;
    const int fk1 = (32 + g * 8) ^ sw;
    int arow[8], brow[4];
#pragma unroll
    for (int mi = 0; mi < 8; ++mi) arow[mi] = (wr + mi * 16 + l15) * 64;
#pragma unroll
    for (int ni = 0; ni < 4; ++ni) brow[ni] = (wc + ni * 16 + l15) * 64;

    f32x4 acc[8][4];
#pragma unroll
    for (int mi = 0; mi < 8; ++mi)
#pragma unroll
        for (int ni = 0; ni < 4; ++ni)
            acc[mi][ni] = (f32x4){0.f, 0.f, 0.f, 0.f};

    auto issueA = [&](int tile) {          // -> A ring slot tile%3
        if (tile >= NT) return;
        unsigned short* rg = sh + (tile % 3) * 16384 + wub;
        const int ka = tile * 64;
        GLD16(gA[0] + ka, rg);
        GLD16(gA[1] + ka, rg + 4096);
        GLD16(gA[2] + ka, rg + 8192);
        GLD16(gA[3] + ka, rg + 12288);
    };
    auto issueB = [&](int tile) {          // -> B dbuf region tile&1
        if (tile >= NT) return;
        unsigned short* rg = sh + 49152 + (tile & 1) * 16384 + wub;
        const int ka = tile * 64;
        GLD16(gB[0] + ka, rg);
        GLD16(gB[1] + ka, rg + 4096);
        GLD16(gB[2] + ka, rg + 8192);
        GLD16(gB[3] + ka, rg + 12288);
    };

    // prologue: order A(0), B(0), A(1) so top vmcnt(4) leaves only A(1)
    issueA(0);
    issueB(0);
    issueA(1);

    bf16x8 af[8], bfr[4];

#define MFMA_32(FK)                                                           \
    __builtin_amdgcn_s_setprio(1);                                            \
    _Pragma("unroll") for (int mi = 0; mi < 8; ++mi)                          \
    _Pragma("unroll") for (int ni = 0; ni < 4; ++ni)                          \
        acc[mi][ni] = __builtin_amdgcn_mfma_f32_16x16x32_bf16(                \
            af[mi], bfr[ni], acc[mi][ni], 0, 0, 0);                           \
    __builtin_amdgcn_s_setprio(0);

    for (int kt = 0; kt < NT; ++kt) {
        const unsigned short* aBase = sh + (kt % 3) * 16384;
        const unsigned short* bBase = sh + 49152 + (kt & 1) * 16384;

        if (kt < NT - 1)
            asm volatile("s_waitcnt vmcnt(4)" ::: "memory");  // tile kt landed
        else
            asm volatile("s_waitcnt vmcnt(0)" ::: "memory");  // final drain
        SBAR();                                               // visible to all

        // ---- phase 0: kk0 ----
#pragma unroll
        for (int ni = 0; ni < 4; ++ni) bfr[ni] = *(const bf16x8*)(bBase + brow[ni] + fk0);
#pragma unroll
        for (int mi = 0; mi < 8; ++mi) af[mi] = *(const bf16x8*)(aBase + arow[mi] + fk0);
        issueB(kt + 1);                                       // region ~cur
        SBAR();
        asm volatile("s_waitcnt lgkmcnt(0)" ::: "memory");
        __builtin_amdgcn_sched_barrier(0);
        MFMA_32(fk0);
        SBAR();

        // ---- phase 1: kk1 ----
#pragma unroll
        for (int ni = 0; ni < 4; ++ni) bfr[ni] = *(const bf16x8*)(bBase + brow[ni] + fk1);
#pragma unroll
        for (int mi = 0; mi < 8; ++mi) af[mi] = *(const bf16x8*)(aBase + arow[mi] + fk1);
        issueA(kt + 2);                                       // ring slot (kt+2)%3
        SBAR();
        asm volatile("s_waitcnt lgkmcnt(0)" ::: "memory");
        __builtin_amdgcn_sched_barrier(0);
        MFMA_32(fk1);
        // trailing barrier merged with next tile's top SBAR
    }
#undef MFMA_32

    // ---- epilogue: C/D layout col=l15, row=g*4+reg ----
    const int orow = bm + wr + g * 4;
    const int ocol = bn + wc + l15;
    float bv[4];
#pragma unroll
    for (int ni = 0; ni < 4; ++ni) bv[ni] = bias[ocol + ni * 16];
#pragma unroll
    for (int mi = 0; mi < 8; ++mi)
#pragma unroll
        for (int ni = 0; ni < 4; ++ni)
#pragma unroll
            for (int r = 0; r < 4; ++r) {
                const int row = orow + mi * 16 + r;
                const int col = ocol + ni * 16;
                const float v = acc[mi][ni][r] + bv[ni];
                if (OUT_BF16)
                    ((unsigned short*)outp)[(size_t)row * N + col] = f2bf(v);
                else
                    ((float*)outp)[(size_t)row * N + col] = v;
            }
}

// ---------------------------------------------------------------------------
// [PROJ] r12's tail-exact 128x160 kernel — measured best (~60 us), kept.
// ---------------------------------------------------------------------------
template <int BN, int OUT_BF16>
__global__ __launch_bounds__(256, 2) void gemm_nt_bf16_g(
    const unsigned short* __restrict__ A,
    const unsigned short* __restrict__ B,
    const float* __restrict__ bias,
    void* __restrict__ outp,
    int N, int nbx)                         // nbx = N/BN
{
    constexpr int NF   = BN / 32;
    constexpr int BBLK = BN / 32;
    constexpr int REG  = (128 + BN) * 64;

    __shared__ unsigned short sh[2 * REG];

    const int t = threadIdx.x;
    const int w = t >> 6;
    const int lane = t & 63;
    const int l15 = lane & 15;
    const int g = lane >> 4;

    const int cpx = gridDim.x >> 3;
    const int bid = blockIdx.x;
    const int wg = (bid & 7) * cpx + (bid >> 3);
    const int bm = (wg / nbx) * 128;
    const int bn = (wg % nbx) * BN;

    const int wr = (w >> 1) * 64;
    const int wc = (w & 1) * (BN / 2);

    const int tr = t >> 3;
    const int colsw = ((t & 7) * 8) ^ (((t >> 3) & 7) << 3);
    const unsigned short* gA[4];
    const unsigned short* gB[BBLK];
#pragma unroll
    for (int j = 0; j < 4; ++j)
        gA[j] = A + (size_t)(bm + j * 32 + tr) * GK + colsw;
#pragma unroll
    for (int j = 0; j < BBLK; ++j)
        gB[j] = B + (size_t)(bn + j * 32 + tr) * GK + colsw;
    const int wub = (t & ~63) * 8;

    const int sw = (l15 & 7) << 3;
    const int fk0 = (g * 8) ^ sw;
    const int fk1 = (32 + g * 8) ^ sw;
    int arow[4], brow[NF];
#pragma unroll
    for (int mi = 0; mi < 4; ++mi) arow[mi] = (wr + mi * 16 + l15) * 64;
#pragma unroll
    for (int ni = 0; ni < NF; ++ni) brow[ni] = 8192 + (wc + ni * 16 + l15) * 64;

    f32x4 acc[4][NF];
#pragma unroll
    for (int mi = 0; mi < 4; ++mi)
#pragma unroll
        for (int ni = 0; ni < NF; ++ni)
            acc[mi][ni] = (f32x4){0.f, 0.f, 0.f, 0.f};

    auto stageTile = [&](int tile) {
        if (tile >= NT) return;
        unsigned short* rg = sh + (tile & 1) * REG + wub;
        const int ka = tile * 64;
#pragma unroll
        for (int j = 0; j < 4; ++j)
            GLD16(gA[j] + ka, rg + j * 2048);
#pragma unroll
        for (int j = 0; j < BBLK; ++j)
            GLD16(gB[j] + ka, rg + 8192 + j * 2048);
    };

    bf16x8 af0[4], af1[4], bf0[NF], bf1[NF];

#define MFMA_PASS(AF, BF)                                                     \
    __builtin_amdgcn_s_setprio(1);                                            \
    _Pragma("unroll") for (int mi = 0; mi < 4; ++mi)                          \
    _Pragma("unroll") for (int ni = 0; ni < NF; ++ni)                         \
        acc[mi][ni] = __builtin_amdgcn_mfma_f32_16x16x32_bf16(                \
            (AF)[mi], (BF)[ni], acc[mi][ni], 0, 0, 0);                        \
    __builtin_amdgcn_s_setprio(0);

    stageTile(0);

    for (int kt = 0; kt < NT; ++kt) {
        const unsigned short* base = sh + (kt & 1) * REG;

        asm volatile("s_waitcnt vmcnt(0)" ::: "memory");
        SBAR();
        stageTile(kt + 1);

#pragma unroll
        for (int ni = 0; ni < NF; ++ni) bf0[ni] = *(const bf16x8*)(base + brow[ni] + fk0);
#pragma unroll
        for (int mi = 0; mi < 4; ++mi) af0[mi] = *(const bf16x8*)(base + arow[mi] + fk0);
#pragma unroll
        for (int ni = 0; ni < NF; ++ni) bf1[ni] = *(const bf16x8*)(base + brow[ni] + fk1);
#pragma unroll
        for (int mi = 0; mi < 4; ++mi) af1[mi] = *(const bf16x8*)(base + arow[mi] + fk1);
        MFMA_PASS(af0, bf0);
        MFMA_PASS(af1, bf1);
    }
#undef MFMA_PASS

    const int orow = bm + wr + g * 4;
    const int ocol = bn + wc + l15;
    float bv[NF];
#pragma unroll
    for (int ni = 0; ni < NF; ++ni) bv[ni] = bias[ocol + ni * 16];
#pragma unroll
    for (int mi = 0; mi < 4; ++mi)
#pragma unroll
        for (int ni = 0; ni < NF; ++ni)
#pragma unroll
            for (int r = 0; r < 4; ++r) {
                const int row = orow + mi * 16 + r;
                const int col = ocol + ni * 16;
                const float v = acc[mi][ni][r] + bv[ni];
                if (OUT_BF16)
                    ((unsigned short*)outp)[(size_t)row * N + col] = f2bf(v);
                else
                    ((float*)outp)[(size_t)row * N + col] = v;
            }
}

// ---------------------------------------------------------------------------
// MFMA windowed attention (unchanged)
// ---------------------------------------------------------------------------
__global__ __launch_bounds__(256) void win_attn_mfma(
    const unsigned short* __restrict__ qkv,  // [S][3840] bf16
    const float* __restrict__ cosb,          // [S][80]
    const float* __restrict__ sinb,          // [S][80]
    const float* __restrict__ mask,          // [NWIN][64][64]
    unsigned short* __restrict__ attn_out)   // [S][1280] bf16
{
    const int h = blockIdx.x;
    const int win = blockIdx.y;
    const int t = threadIdx.x;
    const int w = t >> 6;
    const int lane = t & 63;
    const int l15 = lane & 15;
    const int g = lane >> 4;

    __shared__ unsigned short Qs[64 * 104];
    __shared__ unsigned short Ks[64 * 104];
    __shared__ unsigned short Vt[80 * 88];
    unsigned short* P = Qs;

    const float scale = 0.11180339887498949f;  // 1/sqrt(80)

    for (int c = t; c < 640; c += 256) {
        const int qk = c / 320;
        const int cc = c % 320;
        const int tok = cc / 5;
        const int dd = (cc % 5) * 8;
        const int tokg = win * 64 + tok;
        const size_t gb = (size_t)tokg * QKV_N + h * HD + qk * DIM;
        const bf16x8 lo = *(const bf16x8*)(qkv + gb + dd);
        const bf16x8 hi = *(const bf16x8*)(qkv + gb + dd + 40);
        float cl[8], sl[8], ch[8], sh[8];
        *(float4*)cl = *(const float4*)(cosb + tokg * HD + dd);
        *(float4*)(cl + 4) = *(const float4*)(cosb + tokg * HD + dd + 4);
        *(float4*)sl = *(const float4*)(sinb + tokg * HD + dd);
        *(float4*)(sl + 4) = *(const float4*)(sinb + tokg * HD + dd + 4);
        *(float4*)ch = *(const float4*)(cosb + tokg * HD + dd + 40);
        *(float4*)(ch + 4) = *(const float4*)(cosb + tokg * HD + dd + 44);
        *(float4*)sh = *(const float4*)(sinb + tokg * HD + dd + 40);
        *(float4*)(sh + 4) = *(const float4*)(sinb + tokg * HD + dd + 44);
        ushort8 olo, ohi;
#pragma unroll
        for (int j = 0; j < 8; ++j) {
            const float x1 = bf2f((unsigned short)lo[j]);
            const float x2 = bf2f((unsigned short)hi[j]);
            float rl = x1 * cl[j] - x2 * sl[j];
            float rh = x2 * ch[j] + x1 * sh[j];
            if (qk == 0) { rl *= scale; rh *= scale; }
            olo[j] = f2bf(rl);
            ohi[j] = f2bf(rh);
        }
        unsigned short* base = (qk ? Ks : Qs) + tok * 104 + dd;
        *(ushort8*)base = olo;
        *(ushort8*)(base + 40) = ohi;
    }
    {
        const int tile = t >> 7, row = (t >> 1) & 63, half = t & 1;
        ushort8 z = (ushort8)0;
        *(ushort8*)((tile ? Ks : Qs) + row * 104 + 80 + half * 8) = z;
    }
    for (int c = t; c < 640; c += 256) {
        const int tok = c / 10;
        const int dd = (c % 10) * 8;
        const bf16x8 vv = *(const bf16x8*)(qkv +
            (size_t)(win * 64 + tok) * QKV_N + h * HD + 2 * DIM + dd);
#pragma unroll
        for (int j = 0; j < 8; ++j)
            Vt[(dd + j) * 88 + tok] = (unsigned short)vv[j];
    }
    __syncthreads();

    f32x4 acc[4];
#pragma unroll
    for (int n = 0; n < 4; ++n) acc[n] = (f32x4){0.f, 0.f, 0.f, 0.f};
#pragma unroll
    for (int ks = 0; ks < 3; ++ks) {
        const int k0 = ks * 32;
        const bf16x8 af = *(const bf16x8*)(Qs + (w * 16 + l15) * 104 + k0 + g * 8);
#pragma unroll
        for (int n = 0; n < 4; ++n) {
            const bf16x8 bfr = *(const bf16x8*)(Ks + (n * 16 + l15) * 104 + k0 + g * 8);
            acc[n] = __builtin_amdgcn_mfma_f32_16x16x32_bf16(af, bfr, acc[n], 0, 0, 0);
        }
    }

    const float* mp = mask + (size_t)win * 4096;
    float pr[4][4];
#pragma unroll
    for (int r = 0; r < 4; ++r) {
        const int row = w * 16 + g * 4 + r;
        float v[4];
#pragma unroll
        for (int n = 0; n < 4; ++n)
            v[n] = acc[n][r] + mp[row * 64 + n * 16 + l15];
        float mx = fmaxf(fmaxf(v[0], v[1]), fmaxf(v[2], v[3]));
        mx = fmaxf(mx, __shfl_xor(mx, 1));
        mx = fmaxf(mx, __shfl_xor(mx, 2));
        mx = fmaxf(mx, __shfl_xor(mx, 4));
        mx = fmaxf(mx, __shfl_xor(mx, 8));
        float sum = 0.f;
#pragma unroll
        for (int n = 0; n < 4; ++n) { v[n] = __expf(v[n] - mx); sum += v[n]; }
        sum += __shfl_xor(sum, 1);
        sum += __shfl_xor(sum, 2);
        sum += __shfl_xor(sum, 4);
        sum += __shfl_xor(sum, 8);
        const float inv = 1.0f / sum;
#pragma unroll
        for (int n = 0; n < 4; ++n) pr[r][n] = v[n] * inv;
    }

    __syncthreads();
#pragma unroll
    for (int r = 0; r < 4; ++r)
#pragma unroll
        for (int n = 0; n < 4; ++n)
            P[(w * 16 + g * 4 + r) * 72 + n * 16 + l15] = f2bf(pr[r][n]);
    __syncthreads();

    f32x4 ao[5];
#pragma unroll
    for (int n = 0; n < 5; ++n) ao[n] = (f32x4){0.f, 0.f, 0.f, 0.f};
#pragma unroll
    for (int ks = 0; ks < 2; ++ks) {
        const int k0 = ks * 32;
        const bf16x8 pa = *(const bf16x8*)(P + (w * 16 + l15) * 72 + k0 + g * 8);
#pragma unroll
        for (int n = 0; n < 5; ++n) {
            const bf16x8 bv = *(const bf16x8*)(Vt + (n * 16 + l15) * 88 + k0 + g * 8);
            ao[n] = __builtin_amdgcn_mfma_f32_16x16x32_bf16(pa, bv, ao[n], 0, 0, 0);
        }
    }

#pragma unroll
    for (int n = 0; n < 5; ++n)
#pragma unroll
        for (int r = 0; r < 4; ++r) {
            const int row = win * 64 + w * 16 + g * 4 + r;
            attn_out[(size_t)row * DIM + h * HD + n * 16 + l15] = f2bf(ao[n][r]);
        }
}

// ---------------------------------------------------------------------------
extern "C" void kernel_launch(void* const* d_in, const int* in_sizes, int n_in,
                              void* d_out, int out_size, void* d_ws, size_t ws_size,
                              hipStream_t stream) {
    const float* hidden = (const float*)d_in[0];
    const float* masks  = (const float*)d_in[1];
    const float* cosb   = (const float*)d_in[2];
    const float* sinb   = (const float*)d_in[3];
    const float* qkv_w  = (const float*)d_in[4];
    const float* qkv_b  = (const float*)d_in[5];
    const float* proj_w = (const float*)d_in[6];
    const float* proj_b = (const float*)d_in[7];
    float* out = (float*)d_out;

    unsigned short* qkv_bf    = (unsigned short*)d_ws;                  // [SEQ][3840]
    unsigned short* attn_bf   = qkv_bf    + (size_t)SEQ * QKV_N;        // [SEQ][1280]
    unsigned short* hidden_bf = attn_bf   + (size_t)SEQ * DIM;          // [SEQ][1280]
    unsigned short* qkvw_bf   = hidden_bf + (size_t)SEQ * DIM;          // [3840][1280]
    unsigned short* projw_bf  = qkvw_bf   + (size_t)QKV_N * DIM;        // [1280][1280]

    // 0) merged f32->bf16 converts (one dispatch)
    cvt_all<<<dim3(CVT_B2), 256, 0, stream>>>(hidden, hidden_bf,
                                              qkv_w, qkvw_bf,
                                              proj_w, projw_bf);

    // 1) QKV projection: 64 x 15 = 960 blocks, ring-phased 256x256
    gemm_nt_bf16_r3<1><<<dim3(960), 512, 0, stream>>>(
        hidden_bf, qkvw_bf, qkv_b, (void*)qkv_bf, QKV_N, QKV_N / 256);

    // 2) windowed attention (RoPE fused)
    {
        dim3 grid(NHEAD, NWIN);
        win_attn_mfma<<<grid, 256, 0, stream>>>(qkv_bf, cosb, sinb, masks, attn_bf);
    }

    // 3) output projection: 128x160 tiles -> 1024 blocks @2/CU = 2.00 rounds
    gemm_nt_bf16_g<160, 0><<<dim3(1024), 256, 0, stream>>>(
        attn_bf, projw_bf, proj_b, (void*)out, DIM, DIM / 160);
}

// Round 16
// 303.317 us; speedup vs baseline: 1.0135x; 1.0135x over previous
//
#include <hip/hip_runtime.h>
#include <hip/hip_bf16.h>

#define SEQ 16384
#define DIM 1280
#define NHEAD 16
#define HD 80
#define NWIN 256   // SEQ / 64
#define QKV_N 3840 // 3 * DIM
#define GK 1280    // K of both GEMMs
#define NT 20      // GK / 64

typedef __attribute__((ext_vector_type(8))) short bf16x8;
typedef __attribute__((ext_vector_type(8))) unsigned short ushort8;
typedef __attribute__((ext_vector_type(4))) float f32x4;

__device__ inline unsigned short f2bf(float x) {
    union { __hip_bfloat16 b; unsigned short u; } cv;
    cv.b = __float2bfloat16(x);
    return cv.u;
}
__device__ inline float bf2f(unsigned short u) {
    union { unsigned int i; float f; } cv;
    cv.i = ((unsigned int)u) << 16;
    return cv.f;
}

// async global->LDS, 16B per lane, wave-uniform LDS base + lane*16
#define GLD16(g, l) __builtin_amdgcn_global_load_lds( \
    (const __attribute__((address_space(1))) void*)(g), \
    (__attribute__((address_space(3))) void*)(l), 16, 0, 0)

#define SBAR() asm volatile("s_barrier" ::: "memory")

// ---------------------------------------------------------------------------
// merged f32 -> bf16 convert for all three buffers (one dispatch).
// ---------------------------------------------------------------------------
#define CVT_B0 10240   // SEQ*DIM      / 2048
#define CVT_B1 12640   // + QKV_N*DIM  / 2048
#define CVT_B2 13440   // + DIM*DIM    / 2048
__global__ __launch_bounds__(256) void cvt_all(
    const float* __restrict__ s0, unsigned short* __restrict__ d0,
    const float* __restrict__ s1, unsigned short* __restrict__ d1,
    const float* __restrict__ s2, unsigned short* __restrict__ d2)
{
    const int b = blockIdx.x;
    const float* s; unsigned short* d; long off;
    if (b < CVT_B0)      { s = s0; d = d0; off = (long)b * 2048; }
    else if (b < CVT_B1) { s = s1; d = d1; off = (long)(b - CVT_B0) * 2048; }
    else                 { s = s2; d = d2; off = (long)(b - CVT_B1) * 2048; }
    const long i = off + (long)threadIdx.x * 8;
    const float4 a = *(const float4*)(s + i);
    const float4 c = *(const float4*)(s + i + 4);
    ushort8 o;
    o[0] = f2bf(a.x); o[1] = f2bf(a.y); o[2] = f2bf(a.z); o[3] = f2bf(a.w);
    o[4] = f2bf(c.x); o[5] = f2bf(c.y); o[6] = f2bf(c.z); o[7] = f2bf(c.w);
    *(ushort8*)(d + i) = o;
}

// ---------------------------------------------------------------------------
// [QKV] sp kernel — measured best across 7 schedule variants (161 us,
// MfmaUtil 43.5%, 0 bank conflicts, FETCH 182 MB): 256x256, BK=64, 512
// threads (8 waves 2Mx4N), single-barrier counted loop, sw-pipelined
// ping-pong frags, both-sides 3-bit XOR swizzle, T1 XCD swizzle, T5 setprio.
// ---------------------------------------------------------------------------
template <int OUT_BF16>
__global__ __launch_bounds__(512, 2) void gemm_nt_bf16_sp(
    const unsigned short* __restrict__ A,
    const unsigned short* __restrict__ B,
    const float* __restrict__ bias,
    void* __restrict__ outp,
    int N, int nbx)                         // nbx = N/256
{
    __shared__ unsigned short sh[65536];    // 128 KiB

    const int t = threadIdx.x;
    const int w = t >> 6;
    const int lane = t & 63;
    const int l15 = lane & 15;
    const int g = lane >> 4;

    const int cpx = gridDim.x >> 3;
    const int bid = blockIdx.x;
    const int wg = (bid & 7) * cpx + (bid >> 3);
    const int bm = (wg / nbx) * 256;
    const int bn = (wg % nbx) * 256;

    const int wr = (w >> 2) * 128;
    const int wc = (w & 3) * 64;

    const int colsw = ((t & 7) * 8) ^ (((t >> 3) & 7) << 3);
    const int tr = t >> 3;
    const unsigned short* gA[4];
    const unsigned short* gB[4];
#pragma unroll
    for (int j = 0; j < 4; ++j) {
        gA[j] = A + (size_t)(bm + j * 64 + tr) * GK + colsw;
        gB[j] = B + (size_t)(bn + j * 64 + tr) * GK + colsw;
    }
    const int wub = (t & ~63) * 8;

    const int sw = (l15 & 7) << 3;
    const int fk0 = (g * 8) ^ sw;
    const int fk1 = (32 + g * 8) ^ sw;
    int arow[8], brow[4];
#pragma unroll
    for (int mi = 0; mi < 8; ++mi) arow[mi] = (wr + mi * 16 + l15) * 64;
#pragma unroll
    for (int ni = 0; ni < 4; ++ni) brow[ni] = 16384 + (wc + ni * 16 + l15) * 64;

    f32x4 acc[8][4];
#pragma unroll
    for (int mi = 0; mi < 8; ++mi)
#pragma unroll
        for (int ni = 0; ni < 4; ++ni)
            acc[mi][ni] = (f32x4){0.f, 0.f, 0.f, 0.f};

    auto stageTile = [&](int tile) {
        if (tile >= NT) return;
        unsigned short* rg = sh + (tile & 1) * 32768 + wub;
        const int ka = tile * 64;
        GLD16(gA[0] + ka, rg);
        GLD16(gA[1] + ka, rg + 4096);
        GLD16(gA[2] + ka, rg + 8192);
        GLD16(gA[3] + ka, rg + 12288);
        GLD16(gB[0] + ka, rg + 16384);
        GLD16(gB[1] + ka, rg + 20480);
        GLD16(gB[2] + ka, rg + 24576);
        GLD16(gB[3] + ka, rg + 28672);
    };

    bf16x8 afA[4], afB[4], bfrA[4], bfrB[4];

#define MFMA_QUAD(H, AF, BF)                                                  \
    __builtin_amdgcn_s_setprio(1);                                            \
    _Pragma("unroll") for (int mi = 0; mi < 4; ++mi)                          \
    _Pragma("unroll") for (int ni = 0; ni < 4; ++ni)                          \
        acc[(H) * 4 + mi][ni] = __builtin_amdgcn_mfma_f32_16x16x32_bf16(      \
            (AF)[mi], (BF)[ni], acc[(H) * 4 + mi][ni], 0, 0, 0);              \
    __builtin_amdgcn_s_setprio(0);

    stageTile(0);

    for (int kt = 0; kt < NT; ++kt) {
        const unsigned short* base = sh + (kt & 1) * 32768;

        asm volatile("s_waitcnt vmcnt(0)" ::: "memory");
        SBAR();
        stageTile(kt + 1);

#pragma unroll
        for (int ni = 0; ni < 4; ++ni) bfrA[ni] = *(const bf16x8*)(base + brow[ni] + fk0);
#pragma unroll
        for (int mi = 0; mi < 4; ++mi) afA[mi] = *(const bf16x8*)(base + arow[mi] + fk0);
#pragma unroll
        for (int mi = 0; mi < 4; ++mi) afB[mi] = *(const bf16x8*)(base + arow[4 + mi] + fk0);
        MFMA_QUAD(0, afA, bfrA);
#pragma unroll
        for (int ni = 0; ni < 4; ++ni) bfrB[ni] = *(const bf16x8*)(base + brow[ni] + fk1);
#pragma unroll
        for (int mi = 0; mi < 4; ++mi) afA[mi] = *(const bf16x8*)(base + arow[mi] + fk1);
        MFMA_QUAD(1, afB, bfrA);
#pragma unroll
        for (int mi = 0; mi < 4; ++mi) afB[mi] = *(const bf16x8*)(base + arow[4 + mi] + fk1);
        MFMA_QUAD(0, afA, bfrB);
        MFMA_QUAD(1, afB, bfrB);
    }
#undef MFMA_QUAD

    const int orow = bm + wr + g * 4;
    const int ocol = bn + wc + l15;
    float bv[4];
#pragma unroll
    for (int ni = 0; ni < 4; ++ni) bv[ni] = bias[ocol + ni * 16];
#pragma unroll
    for (int mi = 0; mi < 8; ++mi)
#pragma unroll
        for (int ni = 0; ni < 4; ++ni)
#pragma unroll
            for (int r = 0; r < 4; ++r) {
                const int row = orow + mi * 16 + r;
                const int col = ocol + ni * 16;
                const float v = acc[mi][ni][r] + bv[ni];
                if (OUT_BF16)
                    ((unsigned short*)outp)[(size_t)row * N + col] = f2bf(v);
                else
                    ((float*)outp)[(size_t)row * N + col] = v;
            }
}

// ---------------------------------------------------------------------------
// [PROJ] tail-exact 128x160 kernel — measured best (~60 us).
// ---------------------------------------------------------------------------
template <int BN, int OUT_BF16>
__global__ __launch_bounds__(256, 2) void gemm_nt_bf16_g(
    const unsigned short* __restrict__ A,
    const unsigned short* __restrict__ B,
    const float* __restrict__ bias,
    void* __restrict__ outp,
    int N, int nbx)                         // nbx = N/BN
{
    constexpr int NF   = BN / 32;
    constexpr int BBLK = BN / 32;
    constexpr int REG  = (128 + BN) * 64;

    __shared__ unsigned short sh[2 * REG];

    const int t = threadIdx.x;
    const int w = t >> 6;
    const int lane = t & 63;
    const int l15 = lane & 15;
    const int g = lane >> 4;

    const int cpx = gridDim.x >> 3;
    const int bid = blockIdx.x;
    const int wg = (bid & 7) * cpx + (bid >> 3);
    const int bm = (wg / nbx) * 128;
    const int bn = (wg % nbx) * BN;

    const int wr = (w >> 1) * 64;
    const int wc = (w & 1) * (BN / 2);

    const int tr = t >> 3;
    const int colsw = ((t & 7) * 8) ^ (((t >> 3) & 7) << 3);
    const unsigned short* gA[4];
    const unsigned short* gB[BBLK];
#pragma unroll
    for (int j = 0; j < 4; ++j)
        gA[j] = A + (size_t)(bm + j * 32 + tr) * GK + colsw;
#pragma unroll
    for (int j = 0; j < BBLK; ++j)
        gB[j] = B + (size_t)(bn + j * 32 + tr) * GK + colsw;
    const int wub = (t & ~63) * 8;

    const int sw = (l15 & 7) << 3;
    const int fk0 = (g * 8) ^ sw;
    const int fk1 = (32 + g * 8) ^ sw;
    int arow[4], brow[NF];
#pragma unroll
    for (int mi = 0; mi < 4; ++mi) arow[mi] = (wr + mi * 16 + l15) * 64;
#pragma unroll
    for (int ni = 0; ni < NF; ++ni) brow[ni] = 8192 + (wc + ni * 16 + l15) * 64;

    f32x4 acc[4][NF];
#pragma unroll
    for (int mi = 0; mi < 4; ++mi)
#pragma unroll
        for (int ni = 0; ni < NF; ++ni)
            acc[mi][ni] = (f32x4){0.f, 0.f, 0.f, 0.f};

    auto stageTile = [&](int tile) {
        if (tile >= NT) return;
        unsigned short* rg = sh + (tile & 1) * REG + wub;
        const int ka = tile * 64;
#pragma unroll
        for (int j = 0; j < 4; ++j)
            GLD16(gA[j] + ka, rg + j * 2048);
#pragma unroll
        for (int j = 0; j < BBLK; ++j)
            GLD16(gB[j] + ka, rg + 8192 + j * 2048);
    };

    bf16x8 af0[4], af1[4], bf0[NF], bf1[NF];

#define MFMA_PASS(AF, BF)                                                     \
    __builtin_amdgcn_s_setprio(1);                                            \
    _Pragma("unroll") for (int mi = 0; mi < 4; ++mi)                          \
    _Pragma("unroll") for (int ni = 0; ni < NF; ++ni)                         \
        acc[mi][ni] = __builtin_amdgcn_mfma_f32_16x16x32_bf16(                \
            (AF)[mi], (BF)[ni], acc[mi][ni], 0, 0, 0);                        \
    __builtin_amdgcn_s_setprio(0);

    stageTile(0);

    for (int kt = 0; kt < NT; ++kt) {
        const unsigned short* base = sh + (kt & 1) * REG;

        asm volatile("s_waitcnt vmcnt(0)" ::: "memory");
        SBAR();
        stageTile(kt + 1);

#pragma unroll
        for (int ni = 0; ni < NF; ++ni) bf0[ni] = *(const bf16x8*)(base + brow[ni] + fk0);
#pragma unroll
        for (int mi = 0; mi < 4; ++mi) af0[mi] = *(const bf16x8*)(base + arow[mi] + fk0);
#pragma unroll
        for (int ni = 0; ni < NF; ++ni) bf1[ni] = *(const bf16x8*)(base + brow[ni] + fk1);
#pragma unroll
        for (int mi = 0; mi < 4; ++mi) af1[mi] = *(const bf16x8*)(base + arow[mi] + fk1);
        MFMA_PASS(af0, bf0);
        MFMA_PASS(af1, bf1);
    }
#undef MFMA_PASS

    const int orow = bm + wr + g * 4;
    const int ocol = bn + wc + l15;
    float bv[NF];
#pragma unroll
    for (int ni = 0; ni < NF; ++ni) bv[ni] = bias[ocol + ni * 16];
#pragma unroll
    for (int mi = 0; mi < 4; ++mi)
#pragma unroll
        for (int ni = 0; ni < NF; ++ni)
#pragma unroll
            for (int r = 0; r < 4; ++r) {
                const int row = orow + mi * 16 + r;
                const int col = ocol + ni * 16;
                const float v = acc[mi][ni][r] + bv[ni];
                if (OUT_BF16)
                    ((unsigned short*)outp)[(size_t)row * N + col] = f2bf(v);
                else
                    ((float*)outp)[(size_t)row * N + col] = v;
            }
}

// ---------------------------------------------------------------------------
// MFMA windowed attention (RoPE fused; ~55 us)
// ---------------------------------------------------------------------------
__global__ __launch_bounds__(256) void win_attn_mfma(
    const unsigned short* __restrict__ qkv,  // [S][3840] bf16
    const float* __restrict__ cosb,          // [S][80]
    const float* __restrict__ sinb,          // [S][80]
    const float* __restrict__ mask,          // [NWIN][64][64]
    unsigned short* __restrict__ attn_out)   // [S][1280] bf16
{
    const int h = blockIdx.x;
    const int win = blockIdx.y;
    const int t = threadIdx.x;
    const int w = t >> 6;
    const int lane = t & 63;
    const int l15 = lane & 15;
    const int g = lane >> 4;

    __shared__ unsigned short Qs[64 * 104];
    __shared__ unsigned short Ks[64 * 104];
    __shared__ unsigned short Vt[80 * 88];
    unsigned short* P = Qs;

    const float scale = 0.11180339887498949f;  // 1/sqrt(80)

    for (int c = t; c < 640; c += 256) {
        const int qk = c / 320;
        const int cc = c % 320;
        const int tok = cc / 5;
        const int dd = (cc % 5) * 8;
        const int tokg = win * 64 + tok;
        const size_t gb = (size_t)tokg * QKV_N + h * HD + qk * DIM;
        const bf16x8 lo = *(const bf16x8*)(qkv + gb + dd);
        const bf16x8 hi = *(const bf16x8*)(qkv + gb + dd + 40);
        float cl[8], sl[8], ch[8], sh[8];
        *(float4*)cl = *(const float4*)(cosb + tokg * HD + dd);
        *(float4*)(cl + 4) = *(const float4*)(cosb + tokg * HD + dd + 4);
        *(float4*)sl = *(const float4*)(sinb + tokg * HD + dd);
        *(float4*)(sl + 4) = *(const float4*)(sinb + tokg * HD + dd + 4);
        *(float4*)ch = *(const float4*)(cosb + tokg * HD + dd + 40);
        *(float4*)(ch + 4) = *(const float4*)(cosb + tokg * HD + dd + 44);
        *(float4*)sh = *(const float4*)(sinb + tokg * HD + dd + 40);
        *(float4*)(sh + 4) = *(const float4*)(sinb + tokg * HD + dd + 44);
        ushort8 olo, ohi;
#pragma unroll
        for (int j = 0; j < 8; ++j) {
            const float x1 = bf2f((unsigned short)lo[j]);
            const float x2 = bf2f((unsigned short)hi[j]);
            float rl = x1 * cl[j] - x2 * sl[j];
            float rh = x2 * ch[j] + x1 * sh[j];
            if (qk == 0) { rl *= scale; rh *= scale; }
            olo[j] = f2bf(rl);
            ohi[j] = f2bf(rh);
        }
        unsigned short* base = (qk ? Ks : Qs) + tok * 104 + dd;
        *(ushort8*)base = olo;
        *(ushort8*)(base + 40) = ohi;
    }
    {
        const int tile = t >> 7, row = (t >> 1) & 63, half = t & 1;
        ushort8 z = (ushort8)0;
        *(ushort8*)((tile ? Ks : Qs) + row * 104 + 80 + half * 8) = z;
    }
    for (int c = t; c < 640; c += 256) {
        const int tok = c / 10;
        const int dd = (c % 10) * 8;
        const bf16x8 vv = *(const bf16x8*)(qkv +
            (size_t)(win * 64 + tok) * QKV_N + h * HD + 2 * DIM + dd);
#pragma unroll
        for (int j = 0; j < 8; ++j)
            Vt[(dd + j) * 88 + tok] = (unsigned short)vv[j];
    }
    __syncthreads();

    f32x4 acc[4];
#pragma unroll
    for (int n = 0; n < 4; ++n) acc[n] = (f32x4){0.f, 0.f, 0.f, 0.f};
#pragma unroll
    for (int ks = 0; ks < 3; ++ks) {
        const int k0 = ks * 32;
        const bf16x8 af = *(const bf16x8*)(Qs + (w * 16 + l15) * 104 + k0 + g * 8);
#pragma unroll
        for (int n = 0; n < 4; ++n) {
            const bf16x8 bfr = *(const bf16x8*)(Ks + (n * 16 + l15) * 104 + k0 + g * 8);
            acc[n] = __builtin_amdgcn_mfma_f32_16x16x32_bf16(af, bfr, acc[n], 0, 0, 0);
        }
    }

    const float* mp = mask + (size_t)win * 4096;
    float pr[4][4];
#pragma unroll
    for (int r = 0; r < 4; ++r) {
        const int row = w * 16 + g * 4 + r;
        float v[4];
#pragma unroll
        for (int n = 0; n < 4; ++n)
            v[n] = acc[n][r] + mp[row * 64 + n * 16 + l15];
        float mx = fmaxf(fmaxf(v[0], v[1]), fmaxf(v[2], v[3]));
        mx = fmaxf(mx, __shfl_xor(mx, 1));
        mx = fmaxf(mx, __shfl_xor(mx, 2));
        mx = fmaxf(mx, __shfl_xor(mx, 4));
        mx = fmaxf(mx, __shfl_xor(mx, 8));
        float sum = 0.f;
#pragma unroll
        for (int n = 0; n < 4; ++n) { v[n] = __expf(v[n] - mx); sum += v[n]; }
        sum += __shfl_xor(sum, 1);
        sum += __shfl_xor(sum, 2);
        sum += __shfl_xor(sum, 4);
        sum += __shfl_xor(sum, 8);
        const float inv = 1.0f / sum;
#pragma unroll
        for (int n = 0; n < 4; ++n) pr[r][n] = v[n] * inv;
    }

    __syncthreads();
#pragma unroll
    for (int r = 0; r < 4; ++r)
#pragma unroll
        for (int n = 0; n < 4; ++n)
            P[(w * 16 + g * 4 + r) * 72 + n * 16 + l15] = f2bf(pr[r][n]);
    __syncthreads();

    f32x4 ao[5];
#pragma unroll
    for (int n = 0; n < 5; ++n) ao[n] = (f32x4){0.f, 0.f, 0.f, 0.f};
#pragma unroll
    for (int ks = 0; ks < 2; ++ks) {
        const int k0 = ks * 32;
        const bf16x8 pa = *(const bf16x8*)(P + (w * 16 + l15) * 72 + k0 + g * 8);
#pragma unroll
        for (int n = 0; n < 5; ++n) {
            const bf16x8 bv = *(const bf16x8*)(Vt + (n * 16 + l15) * 88 + k0 + g * 8);
            ao[n] = __builtin_amdgcn_mfma_f32_16x16x32_bf16(pa, bv, ao[n], 0, 0, 0);
        }
    }

#pragma unroll
    for (int n = 0; n < 5; ++n)
#pragma unroll
        for (int r = 0; r < 4; ++r) {
            const int row = win * 64 + w * 16 + g * 4 + r;
            attn_out[(size_t)row * DIM + h * HD + n * 16 + l15] = f2bf(ao[n][r]);
        }
}

// ---------------------------------------------------------------------------
extern "C" void kernel_launch(void* const* d_in, const int* in_sizes, int n_in,
                              void* d_out, int out_size, void* d_ws, size_t ws_size,
                              hipStream_t stream) {
    const float* hidden = (const float*)d_in[0];
    const float* masks  = (const float*)d_in[1];
    const float* cosb   = (const float*)d_in[2];
    const float* sinb   = (const float*)d_in[3];
    const float* qkv_w  = (const float*)d_in[4];
    const float* qkv_b  = (const float*)d_in[5];
    const float* proj_w = (const float*)d_in[6];
    const float* proj_b = (const float*)d_in[7];
    float* out = (float*)d_out;

    unsigned short* qkv_bf    = (unsigned short*)d_ws;                  // [SEQ][3840]
    unsigned short* attn_bf   = qkv_bf    + (size_t)SEQ * QKV_N;        // [SEQ][1280]
    unsigned short* hidden_bf = attn_bf   + (size_t)SEQ * DIM;          // [SEQ][1280]
    unsigned short* qkvw_bf   = hidden_bf + (size_t)SEQ * DIM;          // [3840][1280]
    unsigned short* projw_bf  = qkvw_bf   + (size_t)QKV_N * DIM;        // [1280][1280]

    // 0) merged f32->bf16 converts (one dispatch)
    cvt_all<<<dim3(CVT_B2), 256, 0, stream>>>(hidden, hidden_bf,
                                              qkv_w, qkvw_bf,
                                              proj_w, projw_bf);

    // 1) QKV projection: 64 x 15 = 960 blocks, 256x256 tiles (sp, best)
    gemm_nt_bf16_sp<1><<<dim3(960), 512, 0, stream>>>(
        hidden_bf, qkvw_bf, qkv_b, (void*)qkv_bf, QKV_N, QKV_N / 256);

    // 2) windowed attention (RoPE fused)
    {
        dim3 grid(NHEAD, NWIN);
        win_attn_mfma<<<grid, 256, 0, stream>>>(qkv_bf, cosb, sinb, masks, attn_bf);
    }

    // 3) output projection: 128x160 tiles -> 1024 blocks @2/CU = 2.00 rounds
    gemm_nt_bf16_g<160, 0><<<dim3(1024), 256, 0, stream>>>(
        attn_bf, projw_bf, proj_b, (void*)out, DIM, DIM / 160);
}